// Round 19
// baseline (2029.589 us; speedup 1.0000x reference)
//
#include <hip/hip_runtime.h>
#include <hip/hip_bf16.h>
#include <hip/hip_fp8.h>
#include <stdint.h>

#define BETA 0.5f
#define IGNORE_INDEX (-100)
// Weights pre-scaled x64 into fp8 (avoids e4m3 subnormals for sigma~1/64);
// descale folded into the MX block-scale of B: 2^-6 (E8M0 0x79), exact.
#define WSCALE 64.0f
#define SCALE_ONE  0x7F7F7F7Fu  // E8M0 1.0 per byte
#define SCALE_D64  0x79797979u  // E8M0 2^-6 per byte

typedef float f32x4 __attribute__((ext_vector_type(4)));
typedef int   i32x4 __attribute__((ext_vector_type(4)));
typedef int   i32x8 __attribute__((ext_vector_type(8)));

// ---------------------------------------------------------------- converts
// Grid-stride fused convert, chunk = 8192 floats.  r19: each thread owns 16
// CONSECUTIVE floats per sweep (2 sweeps/chunk) -> output store is one
// 16-B uint4 per sweep (was 4x 4-B stores).  Loads are 16 B/lane, fully
// consumed (no over-fetch).  NT loads (fp32 has zero reuse).
__global__ __launch_bounds__(256) void fused_cvt_kernel(
    const float* __restrict__ s0, uint8_t* __restrict__ d0, int e0,
    const float* __restrict__ s1, uint8_t* __restrict__ d1, int e1,
    const float* __restrict__ s2, uint8_t* __restrict__ d2, int e2,
    const float* __restrict__ s3, uint8_t* __restrict__ d3, int eT) {
  for (int c = blockIdx.x; c < eT; c += gridDim.x) {
    const float* src;
    uint8_t* dst;
    float scale;
    int cb = c;
    if (c < e0)      { src = s0; dst = d0; scale = 1.0f;   }
    else if (c < e1) { src = s1; dst = d1; scale = WSCALE; cb -= e0; }
    else if (c < e2) { src = s2; dst = d2; scale = 1.0f;   cb -= e1; }
    else             { src = s3; dst = d3; scale = WSCALE; cb -= e2; }

    const size_t base = (size_t)cb * 8192 + threadIdx.x * 16;
    f32x4 v[8];
#pragma unroll
    for (int k = 0; k < 4; ++k)
      v[k] = __builtin_nontemporal_load(
          reinterpret_cast<const f32x4*>(src + base + k * 4));
#pragma unroll
    for (int k = 0; k < 4; ++k)
      v[4 + k] = __builtin_nontemporal_load(
          reinterpret_cast<const f32x4*>(src + base + 4096 + k * 4));

    auto pack4 = [&scale](const f32x4& x) -> uint32_t {
      int r = 0;
      r = __builtin_amdgcn_cvt_pk_fp8_f32(x[0] * scale, x[1] * scale, r, false);
      r = __builtin_amdgcn_cvt_pk_fp8_f32(x[2] * scale, x[3] * scale, r, true);
      return (uint32_t)r;
    };
    uint4 o0, o1;
    o0.x = pack4(v[0]); o0.y = pack4(v[1]); o0.z = pack4(v[2]); o0.w = pack4(v[3]);
    o1.x = pack4(v[4]); o1.y = pack4(v[5]); o1.z = pack4(v[6]); o1.w = pack4(v[7]);
    *reinterpret_cast<uint4*>(dst + base)        = o0;
    *reinterpret_cast<uint4*>(dst + base + 4096) = o1;
  }
}

// ---------------------------------------------------------------- GEMM (NT)
// C[n][v] = sum_k A[n][k] * (W[v][k]*64) * 2^-6, A/B fp8 e4m3, C bf16.
// MX K=128 tile-paired on the r13 swizzle chassis (0 conflicts), depth-1
// two-slot staging (race-free, r18).  r19: MID-CLUSTER CERTIFY -- after
// MFMA m=4, vmcnt(0)+s_barrier certifies pair j+1's stage loads landed
// (issued ~1600 cyc earlier at iter start -> drain ~free); then read
// B(j+1) into a second register set (bN) while MFMA m=5..7 (~830 cyc)
// covers the 768-cyc B-burst.  Next iter starts with B in registers ->
// the B-read burst leaves the critical path entirely.  Boundary barrier
// becomes plain (writes drained mid-iter).  Race audit: mid-barrier is
// all-waves (uniform nJ); B(j+1) slot != A-read slot; boundary barrier
// separates iter j's A-reads from iter j+1's STAGE into slot j&1.
// Slot layout: A_E@0  A_O@16K  B_E@32K  B_O@48K  (16 KB each).
// Merged launch: blocks [0,half) = teacher, [half,2*half) = student.

__global__ __launch_bounds__(512, 2) void gemm_mx5_kernel(
    const uint8_t* __restrict__ At, const uint8_t* __restrict__ Bt,
    uint16_t* __restrict__ Ct, int Kt,
    const uint8_t* __restrict__ As_, const uint8_t* __restrict__ Bs_,
    uint16_t* __restrict__ Cs, int Ks,
    int V, int RT, int CT) {
  __shared__ __align__(16) uint8_t lds[131072];

  const int half = RT * CT;
  const uint8_t *A, *B;
  uint16_t* C;
  int K, bidx = blockIdx.x;
  if (bidx < half) { A = At; B = Bt; C = Ct; K = Kt; }
  else             { A = As_; B = Bs_; C = Cs; K = Ks; bidx -= half; }

  int L = ((half & 7) == 0) ? ((bidx & 7) * (half >> 3) + (bidx >> 3)) : bidx;
  const int rt = L % RT;
  const int ct = L / RT;
  const int row0 = rt * 256;
  const int col0 = ct * 256;

  const int i  = threadIdx.x;      // 0..511
  const int w  = i >> 6;
  const int l  = i & 63;
  const int wl = l & 15;
  const int kg = l >> 4;           // quad selector 0..3
  const int wr = w >> 2;           // wave row 0..1 (128 out rows)
  const int wc = w & 3;            // wave col 0..3 (64 out cols)

  const int nJ = K >> 7;           // pairs of BK=64 tiles

  // staging: thread i -> quad (row rg = i>>2, phys pq = i&3), logical quad
  // pq ^ ((rg>>1)&3); rows rg and rg+128 share the XOR term.
  const int rg = i >> 2;           // 0..127
  const int pq = i & 3;
  const int qlog = pq ^ ((rg >> 1) & 3);
  const uint8_t* aSrc = A + (size_t)(row0 + rg) * K + qlog * 16;
  const uint8_t* bSrc = B + (size_t)(col0 + rg) * K + qlog * 16;
  uint8_t* ldsu = lds;

#define GL(srcp, dstp)                                                     \
  __builtin_amdgcn_global_load_lds(                                        \
      (const __attribute__((address_space(1))) void*)(srcp),               \
      (__attribute__((address_space(3))) void*)(dstp), 16, 0, 0)

// Stage pair P (tiles 2P, 2P+1) into slot P&1.  8 loads/thread.
#define STAGE_PAIR(P)                                                      \
  do {                                                                     \
    const size_t _kE = (size_t)(2 * (P)) * 64;                             \
    const size_t _kO = (size_t)(2 * (P) + 1) * 64;                         \
    uint8_t* _sb = ldsu + (((P) & 1) * 65536);                             \
    GL(aSrc + _kE, _sb + i * 16);                                          \
    GL(aSrc + _kE + (size_t)128 * K, _sb + i * 16 + 8192);                 \
    GL(aSrc + _kO, _sb + 16384 + i * 16);                                  \
    GL(aSrc + _kO + (size_t)128 * K, _sb + 16384 + i * 16 + 8192);         \
    GL(bSrc + _kE, _sb + 32768 + i * 16);                                  \
    GL(bSrc + _kE + (size_t)128 * K, _sb + 32768 + i * 16 + 8192);         \
    GL(bSrc + _kO, _sb + 49152 + i * 16);                                  \
    GL(bSrc + _kO + (size_t)128 * K, _sb + 49152 + i * 16 + 8192);         \
  } while (0)

  // ds_read_b128 offsets (within slot): row r, phys quad = kg ^ ((r>>1)&3).
  int offA[8], offB[4];
  const int qsw = (kg ^ ((wl >> 1) & 3)) * 16;
#pragma unroll
  for (int m = 0; m < 8; ++m) {
    const int r = wr * 128 + m * 16 + wl;
    offA[m] = r * 64 + qsw;            // A_E; A_O = +16384
  }
#pragma unroll
  for (int n = 0; n < 4; ++n) {
    const int r = wc * 64 + n * 16 + wl;
    offB[n] = 32768 + r * 64 + qsw;    // B_E; B_O = +16384
  }

  f32x4 acc[8][4] = {};
  i32x8 bF[4], bN[4];

#define LOADA(dst, sp, mm)                                                 \
  do {                                                                     \
    i32x4 _e = *reinterpret_cast<const i32x4*>((sp) + offA[mm]);           \
    i32x4 _o = *reinterpret_cast<const i32x4*>((sp) + offA[mm] + 16384);   \
    dst[0] = _e[0]; dst[1] = _e[1]; dst[2] = _e[2]; dst[3] = _e[3];        \
    dst[4] = _o[0]; dst[5] = _o[1]; dst[6] = _o[2]; dst[7] = _o[3];        \
  } while (0)

#define READB(dst, sp)                                                     \
  do {                                                                     \
    _Pragma("unroll")                                                      \
    for (int _n = 0; _n < 4; ++_n) {                                       \
      i32x4 _be = *reinterpret_cast<const i32x4*>((sp) + offB[_n]);        \
      i32x4 _bo = *reinterpret_cast<const i32x4*>((sp) + offB[_n] + 16384);\
      dst[_n][0] = _be[0]; dst[_n][1] = _be[1];                            \
      dst[_n][2] = _be[2]; dst[_n][3] = _be[3];                            \
      dst[_n][4] = _bo[0]; dst[_n][5] = _bo[1];                            \
      dst[_n][6] = _bo[2]; dst[_n][7] = _bo[3];                            \
    }                                                                      \
  } while (0)

  // prologue: stage pair 0, drain, barrier, read B(0) into bF
  STAGE_PAIR(0);
  asm volatile("s_waitcnt vmcnt(0)" ::: "memory");
  __builtin_amdgcn_s_barrier();
  __builtin_amdgcn_sched_barrier(0);
  READB(bF, lds);

  for (int j = 0; j < nJ; ++j) {
    const uint8_t* sb = lds + (j & 1) * 65536;
    const uint8_t* so = lds + ((j + 1) & 1) * 65536;
    const bool more = (j + 1) < nJ;

    // stage pair j+1 into the OTHER slot (holds pair j-1: consumed and
    // barrier-retired before this iter began -> race-free)
    if (more) STAGE_PAIR(j + 1);

    // MFMA cluster: pipelined A-reads; mid-cluster certify after m=4
    __builtin_amdgcn_s_setprio(1);
    {
      i32x8 aCur, aNxt;
      LOADA(aCur, sb, 0);
#pragma unroll
      for (int m = 0; m < 8; ++m) {
        if (m + 1 < 8) LOADA(aNxt, sb, m + 1);
#pragma unroll
        for (int n = 0; n < 4; ++n)
          acc[m][n] = __builtin_amdgcn_mfma_scale_f32_16x16x128_f8f6f4(
              aCur, bF[n], acc[m][n], 0, 0, 0, SCALE_ONE, 0, SCALE_D64);
        if (m == 4 && more) {
          // certify pair j+1 landed (loads issued ~1600 cyc ago), then
          // read B(j+1) under the shadow of MFMA m=5..7
          __builtin_amdgcn_s_setprio(0);
          asm volatile("s_waitcnt vmcnt(0)" ::: "memory");
          __builtin_amdgcn_s_barrier();
          __builtin_amdgcn_sched_barrier(0);
          READB(bN, so);
          __builtin_amdgcn_s_setprio(1);
        }
        aCur = aNxt;
      }
    }
    __builtin_amdgcn_s_setprio(0);

    // boundary: plain barrier (stage writes drained mid-iter); protects
    // slot j&1 from iter j+1's STAGE_PAIR(j+2)
    if (!more) asm volatile("s_waitcnt vmcnt(0)" ::: "memory");
    __builtin_amdgcn_s_barrier();
    __builtin_amdgcn_sched_barrier(0);

    if (more) {
#pragma unroll
      for (int n = 0; n < 4; ++n) bF[n] = bN[n];
    }
  }

  // epilogue: C/D layout col=lane&15, row=(lane>>4)*4+reg (shape-determined)
#pragma unroll
  for (int mg = 0; mg < 8; ++mg)
#pragma unroll
    for (int ng = 0; ng < 4; ++ng)
#pragma unroll
      for (int r = 0; r < 4; ++r) {
        const int row = row0 + wr * 128 + mg * 16 + kg * 4 + r;
        const int col = col0 + wc * 64 + ng * 16 + wl;
        __hip_bfloat16 bv = __float2bfloat16(acc[mg][ng][r]);
        C[(size_t)row * V + col] = *reinterpret_cast<const uint16_t*>(&bv);
      }
#undef READB
#undef LOADA
#undef STAGE_PAIR
#undef GL
}

// ---------------------------------------------------------------- JSD rows
__device__ __forceinline__ void unpack8(uint4 v, float* f) {
  uint32_t w[4] = {v.x, v.y, v.z, v.w};
#pragma unroll
  for (int j = 0; j < 4; ++j) {
    union { uint32_t u; float x; } lo, hi;
    lo.u = (w[j] & 0xffffu) << 16;
    hi.u = w[j] & 0xffff0000u;
    f[2 * j] = lo.x;
    f[2 * j + 1] = hi.x;
  }
}

__device__ __forceinline__ float blockReduce(float v, float* sh) {
#pragma unroll
  for (int o = 32; o >= 1; o >>= 1) v += __shfl_xor(v, o, 64);
  const int w = threadIdx.x >> 6;
  __syncthreads();
  if ((threadIdx.x & 63) == 0) sh[w] = v;
  __syncthreads();
  float r = sh[0];
#pragma unroll
  for (int i = 1; i < 4; ++i) r += sh[i];
  return r;
}

// online-LSE load pass (1 global sweep, fused max+sum) + 1 LDS JSD pass.
__global__ __launch_bounds__(256) void jsd_rows_kernel(
    const uint16_t* __restrict__ SL, const uint16_t* __restrict__ TL,
    float* __restrict__ per_tok, int V) {
  __shared__ __align__(16) uint16_t rowS[32000];
  __shared__ __align__(16) uint16_t rowT[32000];
  __shared__ float redM[2][4], redS[2][4], red[4];

  const int t = threadIdx.x;
  const int row = blockIdx.x;
  const uint4* gS = reinterpret_cast<const uint4*>(SL + (size_t)row * V);
  const uint4* gT = reinterpret_cast<const uint4*>(TL + (size_t)row * V);
  uint4* lS = reinterpret_cast<uint4*>(rowS);
  uint4* lT = reinterpret_cast<uint4*>(rowT);
  const int nvec = V >> 3;  // 4000

  float mS = -3.0e38f, sS = 0.f, mT = -3.0e38f, sT = 0.f;
  for (int i = t; i < nvec; i += 256) {
    uint4 vs = gS[i], vt = gT[i];
    lS[i] = vs; lT[i] = vt;
    float fs[8], ft[8];
    unpack8(vs, fs);
    unpack8(vt, ft);
    float vmS = fs[0], vmT = ft[0];
#pragma unroll
    for (int j = 1; j < 8; ++j) { vmS = fmaxf(vmS, fs[j]); vmT = fmaxf(vmT, ft[j]); }
    if (vmS > mS) { sS *= __expf(mS - vmS); mS = vmS; }
    if (vmT > mT) { sT *= __expf(mT - vmT); mT = vmT; }
#pragma unroll
    for (int j = 0; j < 8; ++j) { sS += __expf(fs[j] - mS); sT += __expf(ft[j] - mT); }
  }

#pragma unroll
  for (int o = 32; o >= 1; o >>= 1) {
    float mo = __shfl_xor(mS, o, 64), so = __shfl_xor(sS, o, 64);
    float mn = fmaxf(mS, mo);
    sS = sS * __expf(mS - mn) + so * __expf(mo - mn); mS = mn;
    mo = __shfl_xor(mT, o, 64); so = __shfl_xor(sT, o, 64);
    mn = fmaxf(mT, mo);
    sT = sT * __expf(mT - mn) + so * __expf(mo - mn); mT = mn;
  }
  const int wv = t >> 6;
  if ((t & 63) == 0) {
    redM[0][wv] = mS; redS[0][wv] = sS;
    redM[1][wv] = mT; redS[1][wv] = sT;
  }
  __syncthreads();   // covers (m,s) publication AND the LDS row writes
  float M0 = redM[0][0], S0 = redS[0][0];
  float M1 = redM[1][0], S1 = redS[1][0];
#pragma unroll
  for (int k = 1; k < 4; ++k) {
    float m2 = redM[0][k], s2 = redS[0][k];
    float mn = fmaxf(M0, m2);
    S0 = S0 * __expf(M0 - mn) + s2 * __expf(m2 - mn); M0 = mn;
    m2 = redM[1][k]; s2 = redS[1][k];
    mn = fmaxf(M1, m2);
    S1 = S1 * __expf(M1 - mn) + s2 * __expf(m2 - mn); M1 = mn;
  }
  const float lseS = M0 + __logf(S0);
  const float lseT = M1 + __logf(S1);

  float acc = 0.f;
  for (int i = t; i < nvec; i += 256) {
    float fs[8], ft[8];
    unpack8(lS[i], fs);
    unpack8(lT[i], ft);
#pragma unroll
    for (int j = 0; j < 8; ++j) {
      const float lq = fs[j] - lseS;
      const float lp = ft[j] - lseT;
      const float q = __expf(lq);
      const float p = __expf(lp);
      const float m = BETA * p + (1.f - BETA) * q;
      const float lm = __logf(m);
      acc += BETA * p * (lp - lm) + (1.f - BETA) * q * (lq - lm);
    }
  }
  acc = blockReduce(acc, red);
  if (t == 0) per_tok[row] = acc;
}

// ---------------------------------------------------------------- finalize
__global__ __launch_bounds__(256) void finalize_kernel(
    const float* __restrict__ per_tok, const int* __restrict__ tgt,
    float* __restrict__ out, int N) {
  __shared__ float redf[4];
  __shared__ int redi[4];
  float s = 0.f;
  int c = 0;
  for (int i = threadIdx.x; i < N; i += 256) {
    if (tgt[i] != IGNORE_INDEX) { s += per_tok[i]; c += 1; }
  }
#pragma unroll
  for (int o = 32; o >= 1; o >>= 1) {
    s += __shfl_xor(s, o, 64);
    c += __shfl_xor(c, o, 64);
  }
  const int w = threadIdx.x >> 6;
  if ((threadIdx.x & 63) == 0) { redf[w] = s; redi[w] = c; }
  __syncthreads();
  if (threadIdx.x == 0) {
    float st = 0.f;
    int ct = 0;
#pragma unroll
    for (int i = 0; i < 4; ++i) { st += redf[i]; ct += redi[i]; }
    out[0] = st / (float)(ct > 0 ? ct : 1);
  }
}

// ---------------------------------------------------------------- launch
extern "C" void kernel_launch(void* const* d_in, const int* in_sizes, int n_in,
                              void* d_out, int out_size, void* d_ws, size_t ws_size,
                              hipStream_t stream) {
  const float* student = (const float*)d_in[0];
  const float* W_s     = (const float*)d_in[1];
  const float* teacher = (const float*)d_in[2];
  const float* W_t     = (const float*)d_in[3];
  const int*   target  = (const int*)d_in[4];

  const int N  = in_sizes[4];            // 2048
  const int Hs = in_sizes[0] / N;        // 2048
  const int Ht = in_sizes[2] / N;        // 4096
  const int V  = in_sizes[1] / Hs;       // 32000

  char* ws = (char*)d_ws;
  size_t off = 0;
  auto alloc = [&](size_t bytes) -> void* {
    void* p = ws + off;
    off += (bytes + 255) & ~(size_t)255;
    return p;
  };
  uint8_t* Sf8  = (uint8_t*)alloc((size_t)N * Hs);
  uint8_t* Wsf8 = (uint8_t*)alloc((size_t)V * Hs);
  uint8_t* Tf8  = (uint8_t*)alloc((size_t)N * Ht);
  uint8_t* Wtf8 = (uint8_t*)alloc((size_t)V * Ht);
  uint16_t* slog = (uint16_t*)alloc((size_t)N * V * 2);
  uint16_t* tlog = (uint16_t*)alloc((size_t)N * V * 2);
  float* per_tok = (float*)alloc((size_t)N * sizeof(float));
  (void)ws_size;  // total ~465 MB

  // fused convert: grid-stride, 8192-float chunks (boundaries all even
  // multiples of 4096 floats -> no chunk straddles an array)
  const int c0 = (N * Hs) / 8192;               // 512
  const int c1 = c0 + (V * Hs) / 8192;          // +8000
  const int c2 = c1 + (N * Ht) / 8192;          // +1024
  const int cT = c2 + (V * Ht) / 8192;          // +16000 = 25536
  fused_cvt_kernel<<<4096, 256, 0, stream>>>(
      student, Sf8, c0, W_s, Wsf8, c1, teacher, Tf8, c2, W_t, Wtf8, cT);

  const int RT = N / 256;   // 8
  const int CT = V / 256;   // 125
  // merged launch: teacher blocks first, student backfills the tail
  gemm_mx5_kernel<<<2 * RT * CT, 512, 0, stream>>>(
      Tf8, Wtf8, tlog, Ht, Sf8, Wsf8, slog, Hs, V, RT, CT);

  jsd_rows_kernel<<<N, 256, 0, stream>>>(slog, tlog, per_tok, V);
  finalize_kernel<<<1, 256, 0, stream>>>(per_tok, target, (float*)d_out, N);
}

// Round 20
// 824.295 us; speedup vs baseline: 2.4622x; 2.4622x over previous
//
#include <hip/hip_runtime.h>
#include <hip/hip_bf16.h>
#include <hip/hip_fp8.h>
#include <stdint.h>

#define BETA 0.5f
#define IGNORE_INDEX (-100)
// Weights pre-scaled x64 into fp8 (avoids e4m3 subnormals for sigma~1/64);
// descale folded into the MX block-scale of B: 2^-6 (E8M0 0x79), exact.
#define WSCALE 64.0f
#define SCALE_ONE  0x7F7F7F7Fu  // E8M0 1.0 per byte
#define SCALE_D64  0x79797979u  // E8M0 2^-6 per byte

typedef float f32x4 __attribute__((ext_vector_type(4)));
typedef int   i32x4 __attribute__((ext_vector_type(4)));
typedef int   i32x8 __attribute__((ext_vector_type(8)));

// ---------------------------------------------------------------- converts
// Grid-stride fused convert, chunk = 8192 floats.  Each thread owns 16
// consecutive floats per sweep (2 sweeps/chunk) -> one 16-B uint4 store
// per sweep; loads are 16 B/lane, fully consumed.  NT loads (fp32 has
// zero reuse; keep L2 for the fp8 outputs the GEMM re-reads).
__global__ __launch_bounds__(256) void fused_cvt_kernel(
    const float* __restrict__ s0, uint8_t* __restrict__ d0, int e0,
    const float* __restrict__ s1, uint8_t* __restrict__ d1, int e1,
    const float* __restrict__ s2, uint8_t* __restrict__ d2, int e2,
    const float* __restrict__ s3, uint8_t* __restrict__ d3, int eT) {
  for (int c = blockIdx.x; c < eT; c += gridDim.x) {
    const float* src;
    uint8_t* dst;
    float scale;
    int cb = c;
    if (c < e0)      { src = s0; dst = d0; scale = 1.0f;   }
    else if (c < e1) { src = s1; dst = d1; scale = WSCALE; cb -= e0; }
    else if (c < e2) { src = s2; dst = d2; scale = 1.0f;   cb -= e1; }
    else             { src = s3; dst = d3; scale = WSCALE; cb -= e2; }

    const size_t base = (size_t)cb * 8192 + threadIdx.x * 16;
    f32x4 v[8];
#pragma unroll
    for (int k = 0; k < 4; ++k)
      v[k] = __builtin_nontemporal_load(
          reinterpret_cast<const f32x4*>(src + base + k * 4));
#pragma unroll
    for (int k = 0; k < 4; ++k)
      v[4 + k] = __builtin_nontemporal_load(
          reinterpret_cast<const f32x4*>(src + base + 4096 + k * 4));

    auto pack4 = [&scale](const f32x4& x) -> uint32_t {
      int r = 0;
      r = __builtin_amdgcn_cvt_pk_fp8_f32(x[0] * scale, x[1] * scale, r, false);
      r = __builtin_amdgcn_cvt_pk_fp8_f32(x[2] * scale, x[3] * scale, r, true);
      return (uint32_t)r;
    };
    uint4 o0, o1;
    o0.x = pack4(v[0]); o0.y = pack4(v[1]); o0.z = pack4(v[2]); o0.w = pack4(v[3]);
    o1.x = pack4(v[4]); o1.y = pack4(v[5]); o1.z = pack4(v[6]); o1.w = pack4(v[7]);
    *reinterpret_cast<uint4*>(dst + base)        = o0;
    *reinterpret_cast<uint4*>(dst + base + 4096) = o1;
  }
}

// ---------------------------------------------------------------- GEMM (NT)
// r18 VERBATIM (best race-free measured: ~403 us, MfmaUtil 44%, VGPR 100,
// 0 conflicts).  C[n][v] = sum_k A[n][k]*(W[v][k]*64)*2^-6, fp8 e4m3 ->
// bf16.  MX K=128 tile-paired, r13 64-B-row swizzle, pipelined A-reads,
// depth-1 two-slot staging (provably race-free: iter j reads slot j&1,
// stages pair j+1 into the other slot which holds consumed pair j-1).
// r19's mid-cluster B-prefetch REVERTED: the second B register set spilled
// (WRITE_SIZE 256 MB -> 4.4 GB, MfmaUtil 10%) -- at 128 acc VGPRs the
// budget admits exactly one operand set + the A rotation.
// Slot layout: A_E@0  A_O@16K  B_E@32K  B_O@48K  (16 KB each).
// Merged launch: blocks [0,half) = teacher, [half,2*half) = student.

__global__ __launch_bounds__(512, 2) void gemm_mx4_kernel(
    const uint8_t* __restrict__ At, const uint8_t* __restrict__ Bt,
    uint16_t* __restrict__ Ct, int Kt,
    const uint8_t* __restrict__ As_, const uint8_t* __restrict__ Bs_,
    uint16_t* __restrict__ Cs, int Ks,
    int V, int RT, int CT) {
  __shared__ __align__(16) uint8_t lds[131072];

  const int half = RT * CT;
  const uint8_t *A, *B;
  uint16_t* C;
  int K, bidx = blockIdx.x;
  if (bidx < half) { A = At; B = Bt; C = Ct; K = Kt; }
  else             { A = As_; B = Bs_; C = Cs; K = Ks; bidx -= half; }

  int L = ((half & 7) == 0) ? ((bidx & 7) * (half >> 3) + (bidx >> 3)) : bidx;
  const int rt = L % RT;
  const int ct = L / RT;
  const int row0 = rt * 256;
  const int col0 = ct * 256;

  const int i  = threadIdx.x;      // 0..511
  const int w  = i >> 6;
  const int l  = i & 63;
  const int wl = l & 15;
  const int kg = l >> 4;           // quad selector 0..3
  const int wr = w >> 2;           // wave row 0..1 (128 out rows)
  const int wc = w & 3;            // wave col 0..3 (64 out cols)

  const int nJ = K >> 7;           // pairs of BK=64 tiles

  // staging: thread i -> quad (row rg = i>>2, phys pq = i&3), logical quad
  // pq ^ ((rg>>1)&3); rows rg and rg+128 share the XOR term.
  const int rg = i >> 2;           // 0..127
  const int pq = i & 3;
  const int qlog = pq ^ ((rg >> 1) & 3);
  const uint8_t* aSrc = A + (size_t)(row0 + rg) * K + qlog * 16;
  const uint8_t* bSrc = B + (size_t)(col0 + rg) * K + qlog * 16;
  uint8_t* ldsu = lds;

#define GL(srcp, dstp)                                                     \
  __builtin_amdgcn_global_load_lds(                                        \
      (const __attribute__((address_space(1))) void*)(srcp),               \
      (__attribute__((address_space(3))) void*)(dstp), 16, 0, 0)

// Stage pair P (tiles 2P, 2P+1) into slot P&1.  8 loads/thread.
#define STAGE_PAIR(P)                                                      \
  do {                                                                     \
    const size_t _kE = (size_t)(2 * (P)) * 64;                             \
    const size_t _kO = (size_t)(2 * (P) + 1) * 64;                         \
    uint8_t* _sb = ldsu + (((P) & 1) * 65536);                             \
    GL(aSrc + _kE, _sb + i * 16);                                          \
    GL(aSrc + _kE + (size_t)128 * K, _sb + i * 16 + 8192);                 \
    GL(aSrc + _kO, _sb + 16384 + i * 16);                                  \
    GL(aSrc + _kO + (size_t)128 * K, _sb + 16384 + i * 16 + 8192);         \
    GL(bSrc + _kE, _sb + 32768 + i * 16);                                  \
    GL(bSrc + _kE + (size_t)128 * K, _sb + 32768 + i * 16 + 8192);         \
    GL(bSrc + _kO, _sb + 49152 + i * 16);                                  \
    GL(bSrc + _kO + (size_t)128 * K, _sb + 49152 + i * 16 + 8192);         \
  } while (0)

  // ds_read_b128 offsets (within slot): row r, phys quad = kg ^ ((r>>1)&3).
  int offA[8], offB[4];
  const int qsw = (kg ^ ((wl >> 1) & 3)) * 16;
#pragma unroll
  for (int m = 0; m < 8; ++m) {
    const int r = wr * 128 + m * 16 + wl;
    offA[m] = r * 64 + qsw;            // A_E; A_O = +16384
  }
#pragma unroll
  for (int n = 0; n < 4; ++n) {
    const int r = wc * 64 + n * 16 + wl;
    offB[n] = 32768 + r * 64 + qsw;    // B_E; B_O = +16384
  }

  f32x4 acc[8][4] = {};
  i32x8 bF[4];

#define LOADA(dst, mm)                                                     \
  do {                                                                     \
    i32x4 _e = *reinterpret_cast<const i32x4*>(sb + offA[mm]);             \
    i32x4 _o = *reinterpret_cast<const i32x4*>(sb + offA[mm] + 16384);     \
    dst[0] = _e[0]; dst[1] = _e[1]; dst[2] = _e[2]; dst[3] = _e[3];        \
    dst[4] = _o[0]; dst[5] = _o[1]; dst[6] = _o[2]; dst[7] = _o[3];        \
  } while (0)

  // prologue: stage pair 0, drain fully, barrier
  STAGE_PAIR(0);
  asm volatile("s_waitcnt vmcnt(0)" ::: "memory");
  __builtin_amdgcn_s_barrier();
  __builtin_amdgcn_sched_barrier(0);

  for (int j = 0; j < nJ; ++j) {
    const uint8_t* sb = lds + (j & 1) * 65536;

    // B fragments (8 b128) -> bF[0..3]
#pragma unroll
    for (int n = 0; n < 4; ++n) {
      i32x4 be = *reinterpret_cast<const i32x4*>(sb + offB[n]);
      i32x4 bo = *reinterpret_cast<const i32x4*>(sb + offB[n] + 16384);
      bF[n][0] = be[0]; bF[n][1] = be[1]; bF[n][2] = be[2]; bF[n][3] = be[3];
      bF[n][4] = bo[0]; bF[n][5] = bo[1]; bF[n][6] = bo[2]; bF[n][7] = bo[3];
    }

    // stage pair j+1 into the OTHER slot (holds pair j-1: consumed and
    // barrier-retired before this iter began -> provably race-free)
    if (j + 1 < nJ) STAGE_PAIR(j + 1);

    // MFMA cluster with pipelined A-reads: read(m+1) before MFMA(m)
    __builtin_amdgcn_s_setprio(1);
    {
      i32x8 aCur, aNxt;
      LOADA(aCur, 0);
#pragma unroll
      for (int m = 0; m < 8; ++m) {
        if (m + 1 < 8) LOADA(aNxt, m + 1);
#pragma unroll
        for (int n = 0; n < 4; ++n)
          acc[m][n] = __builtin_amdgcn_mfma_scale_f32_16x16x128_f8f6f4(
              aCur, bF[n], acc[m][n], 0, 0, 0, SCALE_ONE, 0, SCALE_D64);
        aCur = aNxt;
      }
    }
    __builtin_amdgcn_s_setprio(0);

    // boundary: drain stage (issued ~2500 cyc ago -> ~free), barrier
    asm volatile("s_waitcnt vmcnt(0)" ::: "memory");
    __builtin_amdgcn_s_barrier();
    __builtin_amdgcn_sched_barrier(0);
  }

  // epilogue: C/D layout col=lane&15, row=(lane>>4)*4+reg (shape-determined)
#pragma unroll
  for (int mg = 0; mg < 8; ++mg)
#pragma unroll
    for (int ng = 0; ng < 4; ++ng)
#pragma unroll
      for (int r = 0; r < 4; ++r) {
        const int row = row0 + wr * 128 + mg * 16 + kg * 4 + r;
        const int col = col0 + wc * 64 + ng * 16 + wl;
        __hip_bfloat16 bv = __float2bfloat16(acc[mg][ng][r]);
        C[(size_t)row * V + col] = *reinterpret_cast<const uint16_t*>(&bv);
      }
#undef LOADA
#undef STAGE_PAIR
#undef GL
}

// ---------------------------------------------------------------- JSD rows
__device__ __forceinline__ void unpack8(uint4 v, float* f) {
  uint32_t w[4] = {v.x, v.y, v.z, v.w};
#pragma unroll
  for (int j = 0; j < 4; ++j) {
    union { uint32_t u; float x; } lo, hi;
    lo.u = (w[j] & 0xffffu) << 16;
    hi.u = w[j] & 0xffff0000u;
    f[2 * j] = lo.x;
    f[2 * j + 1] = hi.x;
  }
}

__device__ __forceinline__ float blockReduce(float v, float* sh) {
#pragma unroll
  for (int o = 32; o >= 1; o >>= 1) v += __shfl_xor(v, o, 64);
  const int w = threadIdx.x >> 6;
  __syncthreads();
  if ((threadIdx.x & 63) == 0) sh[w] = v;
  __syncthreads();
  float r = sh[0];
#pragma unroll
  for (int i = 1; i < 4; ++i) r += sh[i];
  return r;
}

// online-LSE load pass (1 global sweep, fused max+sum) + 1 LDS JSD pass.
__global__ __launch_bounds__(256) void jsd_rows_kernel(
    const uint16_t* __restrict__ SL, const uint16_t* __restrict__ TL,
    float* __restrict__ per_tok, int V) {
  __shared__ __align__(16) uint16_t rowS[32000];
  __shared__ __align__(16) uint16_t rowT[32000];
  __shared__ float redM[2][4], redS[2][4], red[4];

  const int t = threadIdx.x;
  const int row = blockIdx.x;
  const uint4* gS = reinterpret_cast<const uint4*>(SL + (size_t)row * V);
  const uint4* gT = reinterpret_cast<const uint4*>(TL + (size_t)row * V);
  uint4* lS = reinterpret_cast<uint4*>(rowS);
  uint4* lT = reinterpret_cast<uint4*>(rowT);
  const int nvec = V >> 3;  // 4000

  float mS = -3.0e38f, sS = 0.f, mT = -3.0e38f, sT = 0.f;
  for (int i = t; i < nvec; i += 256) {
    uint4 vs = gS[i], vt = gT[i];
    lS[i] = vs; lT[i] = vt;
    float fs[8], ft[8];
    unpack8(vs, fs);
    unpack8(vt, ft);
    float vmS = fs[0], vmT = ft[0];
#pragma unroll
    for (int j = 1; j < 8; ++j) { vmS = fmaxf(vmS, fs[j]); vmT = fmaxf(vmT, ft[j]); }
    if (vmS > mS) { sS *= __expf(mS - vmS); mS = vmS; }
    if (vmT > mT) { sT *= __expf(mT - vmT); mT = vmT; }
#pragma unroll
    for (int j = 0; j < 8; ++j) { sS += __expf(fs[j] - mS); sT += __expf(ft[j] - mT); }
  }

#pragma unroll
  for (int o = 32; o >= 1; o >>= 1) {
    float mo = __shfl_xor(mS, o, 64), so = __shfl_xor(sS, o, 64);
    float mn = fmaxf(mS, mo);
    sS = sS * __expf(mS - mn) + so * __expf(mo - mn); mS = mn;
    mo = __shfl_xor(mT, o, 64); so = __shfl_xor(sT, o, 64);
    mn = fmaxf(mT, mo);
    sT = sT * __expf(mT - mn) + so * __expf(mo - mn); mT = mn;
  }
  const int wv = t >> 6;
  if ((t & 63) == 0) {
    redM[0][wv] = mS; redS[0][wv] = sS;
    redM[1][wv] = mT; redS[1][wv] = sT;
  }
  __syncthreads();   // covers (m,s) publication AND the LDS row writes
  float M0 = redM[0][0], S0 = redS[0][0];
  float M1 = redM[1][0], S1 = redS[1][0];
#pragma unroll
  for (int k = 1; k < 4; ++k) {
    float m2 = redM[0][k], s2 = redS[0][k];
    float mn = fmaxf(M0, m2);
    S0 = S0 * __expf(M0 - mn) + s2 * __expf(m2 - mn); M0 = mn;
    m2 = redM[1][k]; s2 = redS[1][k];
    mn = fmaxf(M1, m2);
    S1 = S1 * __expf(M1 - mn) + s2 * __expf(m2 - mn); M1 = mn;
  }
  const float lseS = M0 + __logf(S0);
  const float lseT = M1 + __logf(S1);

  float acc = 0.f;
  for (int i = t; i < nvec; i += 256) {
    float fs[8], ft[8];
    unpack8(lS[i], fs);
    unpack8(lT[i], ft);
#pragma unroll
    for (int j = 0; j < 8; ++j) {
      const float lq = fs[j] - lseS;
      const float lp = ft[j] - lseT;
      const float q = __expf(lq);
      const float p = __expf(lp);
      const float m = BETA * p + (1.f - BETA) * q;
      const float lm = __logf(m);
      acc += BETA * p * (lp - lm) + (1.f - BETA) * q * (lq - lm);
    }
  }
  acc = blockReduce(acc, red);
  if (t == 0) per_tok[row] = acc;
}

// ---------------------------------------------------------------- finalize
__global__ __launch_bounds__(256) void finalize_kernel(
    const float* __restrict__ per_tok, const int* __restrict__ tgt,
    float* __restrict__ out, int N) {
  __shared__ float redf[4];
  __shared__ int redi[4];
  float s = 0.f;
  int c = 0;
  for (int i = threadIdx.x; i < N; i += 256) {
    if (tgt[i] != IGNORE_INDEX) { s += per_tok[i]; c += 1; }
  }
#pragma unroll
  for (int o = 32; o >= 1; o >>= 1) {
    s += __shfl_xor(s, o, 64);
    c += __shfl_xor(c, o, 64);
  }
  const int w = threadIdx.x >> 6;
  if ((threadIdx.x & 63) == 0) { redf[w] = s; redi[w] = c; }
  __syncthreads();
  if (threadIdx.x == 0) {
    float st = 0.f;
    int ct = 0;
#pragma unroll
    for (int i = 0; i < 4; ++i) { st += redf[i]; ct += redi[i]; }
    out[0] = st / (float)(ct > 0 ? ct : 1);
  }
}

// ---------------------------------------------------------------- launch
extern "C" void kernel_launch(void* const* d_in, const int* in_sizes, int n_in,
                              void* d_out, int out_size, void* d_ws, size_t ws_size,
                              hipStream_t stream) {
  const float* student = (const float*)d_in[0];
  const float* W_s     = (const float*)d_in[1];
  const float* teacher = (const float*)d_in[2];
  const float* W_t     = (const float*)d_in[3];
  const int*   target  = (const int*)d_in[4];

  const int N  = in_sizes[4];            // 2048
  const int Hs = in_sizes[0] / N;        // 2048
  const int Ht = in_sizes[2] / N;        // 4096
  const int V  = in_sizes[1] / Hs;       // 32000

  char* ws = (char*)d_ws;
  size_t off = 0;
  auto alloc = [&](size_t bytes) -> void* {
    void* p = ws + off;
    off += (bytes + 255) & ~(size_t)255;
    return p;
  };
  uint8_t* Sf8  = (uint8_t*)alloc((size_t)N * Hs);
  uint8_t* Wsf8 = (uint8_t*)alloc((size_t)V * Hs);
  uint8_t* Tf8  = (uint8_t*)alloc((size_t)N * Ht);
  uint8_t* Wtf8 = (uint8_t*)alloc((size_t)V * Ht);
  uint16_t* slog = (uint16_t*)alloc((size_t)N * V * 2);
  uint16_t* tlog = (uint16_t*)alloc((size_t)N * V * 2);
  float* per_tok = (float*)alloc((size_t)N * sizeof(float));
  (void)ws_size;  // total ~465 MB

  // fused convert: grid-stride, 8192-float chunks (boundaries all even
  // multiples of 4096 floats -> no chunk straddles an array)
  const int c0 = (N * Hs) / 8192;               // 512
  const int c1 = c0 + (V * Hs) / 8192;          // +8000
  const int c2 = c1 + (N * Ht) / 8192;          // +1024
  const int cT = c2 + (V * Ht) / 8192;          // +16000 = 25536
  fused_cvt_kernel<<<4096, 256, 0, stream>>>(
      student, Sf8, c0, W_s, Wsf8, c1, teacher, Tf8, c2, W_t, Wtf8, cT);

  const int RT = N / 256;   // 8
  const int CT = V / 256;   // 125
  // merged launch: teacher blocks first, student backfills the tail
  gemm_mx4_kernel<<<2 * RT * CT, 512, 0, stream>>>(
      Tf8, Wtf8, tlog, Ht, Sf8, Wsf8, slog, Hs, V, RT, CT);

  jsd_rows_kernel<<<N, 256, 0, stream>>>(slog, tlog, per_tok, V);
  finalize_kernel<<<1, 256, 0, stream>>>(per_tok, target, (float*)d_out, N);
}

// Round 21
// 725.621 us; speedup vs baseline: 2.7970x; 1.1360x over previous
//
#include <hip/hip_runtime.h>
#include <hip/hip_bf16.h>
#include <hip/hip_fp8.h>
#include <stdint.h>

#define BETA 0.5f
#define IGNORE_INDEX (-100)
// Weights pre-scaled x64 into fp8 (avoids e4m3 subnormals for sigma~1/64);
// descale folded into the MX block-scale of B: 2^-6 (E8M0 0x79), exact.
#define WSCALE 64.0f
#define SCALE_ONE  0x7F7F7F7Fu  // E8M0 1.0 per byte
#define SCALE_D64  0x79797979u  // E8M0 2^-6 per byte

typedef float f32x4 __attribute__((ext_vector_type(4)));
typedef int   i32x4 __attribute__((ext_vector_type(4)));
typedef int   i32x8 __attribute__((ext_vector_type(8)));

// ---------------------------------------------------------------- converts
// r18 layout RESTORED: thread t owns floats t*4 + k*1024 (k=0..7) ->
// every f32x4 load has lane stride 16 B (= load width, wave-contiguous)
// and every u32 store has lane stride 4 B (= store width).  r19/r20's
// consecutive-16-float variant made load lane-stride 64 B (4x transactions)
// and cost ~100 us.  Grid-stride over 8192-float chunks; all array
// boundaries are even multiples of 4096 floats so chunks never straddle.
__global__ __launch_bounds__(256) void fused_cvt_kernel(
    const float* __restrict__ s0, uint8_t* __restrict__ d0, int e0,
    const float* __restrict__ s1, uint8_t* __restrict__ d1, int e1,
    const float* __restrict__ s2, uint8_t* __restrict__ d2, int e2,
    const float* __restrict__ s3, uint8_t* __restrict__ d3, int eT) {
  for (int c = blockIdx.x; c < eT; c += gridDim.x) {
    const float* src;
    uint8_t* dst;
    float scale;
    int cb = c;
    if (c < e0)      { src = s0; dst = d0; scale = 1.0f;   }
    else if (c < e1) { src = s1; dst = d1; scale = WSCALE; cb -= e0; }
    else if (c < e2) { src = s2; dst = d2; scale = 1.0f;   cb -= e1; }
    else             { src = s3; dst = d3; scale = WSCALE; cb -= e2; }

    const size_t base = (size_t)cb * 8192 + threadIdx.x * 4;
    f32x4 v[8];
#pragma unroll
    for (int k = 0; k < 8; ++k)
      v[k] = __builtin_nontemporal_load(
          reinterpret_cast<const f32x4*>(src + base + k * 1024));
#pragma unroll
    for (int k = 0; k < 8; ++k) {
      int r = 0;
      r = __builtin_amdgcn_cvt_pk_fp8_f32(v[k][0] * scale, v[k][1] * scale, r, false);
      r = __builtin_amdgcn_cvt_pk_fp8_f32(v[k][2] * scale, v[k][3] * scale, r, true);
      *reinterpret_cast<uint32_t*>(dst + base + k * 1024) = (uint32_t)r;
    }
  }
}

// ---------------------------------------------------------------- GEMM (NT)
// r18 VERBATIM (best race-free measured: ~407 us, MfmaUtil 44%, VGPR 100,
// 0 conflicts).  C[n][v] = sum_k A[n][k]*(W[v][k]*64)*2^-6, fp8 e4m3 ->
// bf16.  MX K=128 tile-paired, r13 64-B-row swizzle, pipelined A-reads,
// depth-1 two-slot staging (provably race-free: iter j reads slot j&1,
// stages pair j+1 into the other slot which holds consumed pair j-1).
// Slot layout: A_E@0  A_O@16K  B_E@32K  B_O@48K  (16 KB each).
// Merged launch: blocks [0,half) = teacher, [half,2*half) = student.

__global__ __launch_bounds__(512, 2) void gemm_mx4_kernel(
    const uint8_t* __restrict__ At, const uint8_t* __restrict__ Bt,
    uint16_t* __restrict__ Ct, int Kt,
    const uint8_t* __restrict__ As_, const uint8_t* __restrict__ Bs_,
    uint16_t* __restrict__ Cs, int Ks,
    int V, int RT, int CT) {
  __shared__ __align__(16) uint8_t lds[131072];

  const int half = RT * CT;
  const uint8_t *A, *B;
  uint16_t* C;
  int K, bidx = blockIdx.x;
  if (bidx < half) { A = At; B = Bt; C = Ct; K = Kt; }
  else             { A = As_; B = Bs_; C = Cs; K = Ks; bidx -= half; }

  int L = ((half & 7) == 0) ? ((bidx & 7) * (half >> 3) + (bidx >> 3)) : bidx;
  const int rt = L % RT;
  const int ct = L / RT;
  const int row0 = rt * 256;
  const int col0 = ct * 256;

  const int i  = threadIdx.x;      // 0..511
  const int w  = i >> 6;
  const int l  = i & 63;
  const int wl = l & 15;
  const int kg = l >> 4;           // quad selector 0..3
  const int wr = w >> 2;           // wave row 0..1 (128 out rows)
  const int wc = w & 3;            // wave col 0..3 (64 out cols)

  const int nJ = K >> 7;           // pairs of BK=64 tiles

  // staging: thread i -> quad (row rg = i>>2, phys pq = i&3), logical quad
  // pq ^ ((rg>>1)&3); rows rg and rg+128 share the XOR term.
  const int rg = i >> 2;           // 0..127
  const int pq = i & 3;
  const int qlog = pq ^ ((rg >> 1) & 3);
  const uint8_t* aSrc = A + (size_t)(row0 + rg) * K + qlog * 16;
  const uint8_t* bSrc = B + (size_t)(col0 + rg) * K + qlog * 16;
  uint8_t* ldsu = lds;

#define GL(srcp, dstp)                                                     \
  __builtin_amdgcn_global_load_lds(                                        \
      (const __attribute__((address_space(1))) void*)(srcp),               \
      (__attribute__((address_space(3))) void*)(dstp), 16, 0, 0)

// Stage pair P (tiles 2P, 2P+1) into slot P&1.  8 loads/thread.
#define STAGE_PAIR(P)                                                      \
  do {                                                                     \
    const size_t _kE = (size_t)(2 * (P)) * 64;                             \
    const size_t _kO = (size_t)(2 * (P) + 1) * 64;                         \
    uint8_t* _sb = ldsu + (((P) & 1) * 65536);                             \
    GL(aSrc + _kE, _sb + i * 16);                                          \
    GL(aSrc + _kE + (size_t)128 * K, _sb + i * 16 + 8192);                 \
    GL(aSrc + _kO, _sb + 16384 + i * 16);                                  \
    GL(aSrc + _kO + (size_t)128 * K, _sb + 16384 + i * 16 + 8192);         \
    GL(bSrc + _kE, _sb + 32768 + i * 16);                                  \
    GL(bSrc + _kE + (size_t)128 * K, _sb + 32768 + i * 16 + 8192);         \
    GL(bSrc + _kO, _sb + 49152 + i * 16);                                  \
    GL(bSrc + _kO + (size_t)128 * K, _sb + 49152 + i * 16 + 8192);         \
  } while (0)

  // ds_read_b128 offsets (within slot): row r, phys quad = kg ^ ((r>>1)&3).
  int offA[8], offB[4];
  const int qsw = (kg ^ ((wl >> 1) & 3)) * 16;
#pragma unroll
  for (int m = 0; m < 8; ++m) {
    const int r = wr * 128 + m * 16 + wl;
    offA[m] = r * 64 + qsw;            // A_E; A_O = +16384
  }
#pragma unroll
  for (int n = 0; n < 4; ++n) {
    const int r = wc * 64 + n * 16 + wl;
    offB[n] = 32768 + r * 64 + qsw;    // B_E; B_O = +16384
  }

  f32x4 acc[8][4] = {};
  i32x8 bF[4];

#define LOADA(dst, mm)                                                     \
  do {                                                                     \
    i32x4 _e = *reinterpret_cast<const i32x4*>(sb + offA[mm]);             \
    i32x4 _o = *reinterpret_cast<const i32x4*>(sb + offA[mm] + 16384);     \
    dst[0] = _e[0]; dst[1] = _e[1]; dst[2] = _e[2]; dst[3] = _e[3];        \
    dst[4] = _o[0]; dst[5] = _o[1]; dst[6] = _o[2]; dst[7] = _o[3];        \
  } while (0)

  // prologue: stage pair 0, drain fully, barrier
  STAGE_PAIR(0);
  asm volatile("s_waitcnt vmcnt(0)" ::: "memory");
  __builtin_amdgcn_s_barrier();
  __builtin_amdgcn_sched_barrier(0);

  for (int j = 0; j < nJ; ++j) {
    const uint8_t* sb = lds + (j & 1) * 65536;

    // B fragments (8 b128) -> bF[0..3]
#pragma unroll
    for (int n = 0; n < 4; ++n) {
      i32x4 be = *reinterpret_cast<const i32x4*>(sb + offB[n]);
      i32x4 bo = *reinterpret_cast<const i32x4*>(sb + offB[n] + 16384);
      bF[n][0] = be[0]; bF[n][1] = be[1]; bF[n][2] = be[2]; bF[n][3] = be[3];
      bF[n][4] = bo[0]; bF[n][5] = bo[1]; bF[n][6] = bo[2]; bF[n][7] = bo[3];
    }

    // stage pair j+1 into the OTHER slot (holds pair j-1: consumed and
    // barrier-retired before this iter began -> provably race-free)
    if (j + 1 < nJ) STAGE_PAIR(j + 1);

    // MFMA cluster with pipelined A-reads: read(m+1) before MFMA(m)
    __builtin_amdgcn_s_setprio(1);
    {
      i32x8 aCur, aNxt;
      LOADA(aCur, 0);
#pragma unroll
      for (int m = 0; m < 8; ++m) {
        if (m + 1 < 8) LOADA(aNxt, m + 1);
#pragma unroll
        for (int n = 0; n < 4; ++n)
          acc[m][n] = __builtin_amdgcn_mfma_scale_f32_16x16x128_f8f6f4(
              aCur, bF[n], acc[m][n], 0, 0, 0, SCALE_ONE, 0, SCALE_D64);
        aCur = aNxt;
      }
    }
    __builtin_amdgcn_s_setprio(0);

    // boundary: drain stage (issued ~2500 cyc ago -> ~free), barrier
    asm volatile("s_waitcnt vmcnt(0)" ::: "memory");
    __builtin_amdgcn_s_barrier();
    __builtin_amdgcn_sched_barrier(0);
  }

  // epilogue: C/D layout col=lane&15, row=(lane>>4)*4+reg (shape-determined)
#pragma unroll
  for (int mg = 0; mg < 8; ++mg)
#pragma unroll
    for (int ng = 0; ng < 4; ++ng)
#pragma unroll
      for (int r = 0; r < 4; ++r) {
        const int row = row0 + wr * 128 + mg * 16 + kg * 4 + r;
        const int col = col0 + wc * 64 + ng * 16 + wl;
        __hip_bfloat16 bv = __float2bfloat16(acc[mg][ng][r]);
        C[(size_t)row * V + col] = *reinterpret_cast<const uint16_t*>(&bv);
      }
#undef LOADA
#undef STAGE_PAIR
#undef GL
}

// ---------------------------------------------------------------- JSD rows
__device__ __forceinline__ void unpack8(uint4 v, float* f) {
  uint32_t w[4] = {v.x, v.y, v.z, v.w};
#pragma unroll
  for (int j = 0; j < 4; ++j) {
    union { uint32_t u; float x; } lo, hi;
    lo.u = (w[j] & 0xffffu) << 16;
    hi.u = w[j] & 0xffff0000u;
    f[2 * j] = lo.x;
    f[2 * j + 1] = hi.x;
  }
}

__device__ __forceinline__ float blockReduce(float v, float* sh) {
#pragma unroll
  for (int o = 32; o >= 1; o >>= 1) v += __shfl_xor(v, o, 64);
  const int w = threadIdx.x >> 6;
  __syncthreads();
  if ((threadIdx.x & 63) == 0) sh[w] = v;
  __syncthreads();
  float r = sh[0];
#pragma unroll
  for (int i = 1; i < 4; ++i) r += sh[i];
  return r;
}

// online-LSE load pass (1 global sweep, fused max+sum) + 1 LDS JSD pass.
__global__ __launch_bounds__(256) void jsd_rows_kernel(
    const uint16_t* __restrict__ SL, const uint16_t* __restrict__ TL,
    float* __restrict__ per_tok, int V) {
  __shared__ __align__(16) uint16_t rowS[32000];
  __shared__ __align__(16) uint16_t rowT[32000];
  __shared__ float redM[2][4], redS[2][4], red[4];

  const int t = threadIdx.x;
  const int row = blockIdx.x;
  const uint4* gS = reinterpret_cast<const uint4*>(SL + (size_t)row * V);
  const uint4* gT = reinterpret_cast<const uint4*>(TL + (size_t)row * V);
  uint4* lS = reinterpret_cast<uint4*>(rowS);
  uint4* lT = reinterpret_cast<uint4*>(rowT);
  const int nvec = V >> 3;  // 4000

  float mS = -3.0e38f, sS = 0.f, mT = -3.0e38f, sT = 0.f;
  for (int i = t; i < nvec; i += 256) {
    uint4 vs = gS[i], vt = gT[i];
    lS[i] = vs; lT[i] = vt;
    float fs[8], ft[8];
    unpack8(vs, fs);
    unpack8(vt, ft);
    float vmS = fs[0], vmT = ft[0];
#pragma unroll
    for (int j = 1; j < 8; ++j) { vmS = fmaxf(vmS, fs[j]); vmT = fmaxf(vmT, ft[j]); }
    if (vmS > mS) { sS *= __expf(mS - vmS); mS = vmS; }
    if (vmT > mT) { sT *= __expf(mT - vmT); mT = vmT; }
#pragma unroll
    for (int j = 0; j < 8; ++j) { sS += __expf(fs[j] - mS); sT += __expf(ft[j] - mT); }
  }

#pragma unroll
  for (int o = 32; o >= 1; o >>= 1) {
    float mo = __shfl_xor(mS, o, 64), so = __shfl_xor(sS, o, 64);
    float mn = fmaxf(mS, mo);
    sS = sS * __expf(mS - mn) + so * __expf(mo - mn); mS = mn;
    mo = __shfl_xor(mT, o, 64); so = __shfl_xor(sT, o, 64);
    mn = fmaxf(mT, mo);
    sT = sT * __expf(mT - mn) + so * __expf(mo - mn); mT = mn;
  }
  const int wv = t >> 6;
  if ((t & 63) == 0) {
    redM[0][wv] = mS; redS[0][wv] = sS;
    redM[1][wv] = mT; redS[1][wv] = sT;
  }
  __syncthreads();   // covers (m,s) publication AND the LDS row writes
  float M0 = redM[0][0], S0 = redS[0][0];
  float M1 = redM[1][0], S1 = redS[1][0];
#pragma unroll
  for (int k = 1; k < 4; ++k) {
    float m2 = redM[0][k], s2 = redS[0][k];
    float mn = fmaxf(M0, m2);
    S0 = S0 * __expf(M0 - mn) + s2 * __expf(m2 - mn); M0 = mn;
    m2 = redM[1][k]; s2 = redS[1][k];
    mn = fmaxf(M1, m2);
    S1 = S1 * __expf(M1 - mn) + s2 * __expf(m2 - mn); M1 = mn;
  }
  const float lseS = M0 + __logf(S0);
  const float lseT = M1 + __logf(S1);

  float acc = 0.f;
  for (int i = t; i < nvec; i += 256) {
    float fs[8], ft[8];
    unpack8(lS[i], fs);
    unpack8(lT[i], ft);
#pragma unroll
    for (int j = 0; j < 8; ++j) {
      const float lq = fs[j] - lseS;
      const float lp = ft[j] - lseT;
      const float q = __expf(lq);
      const float p = __expf(lp);
      const float m = BETA * p + (1.f - BETA) * q;
      const float lm = __logf(m);
      acc += BETA * p * (lp - lm) + (1.f - BETA) * q * (lq - lm);
    }
  }
  acc = blockReduce(acc, red);
  if (t == 0) per_tok[row] = acc;
}

// ---------------------------------------------------------------- finalize
__global__ __launch_bounds__(256) void finalize_kernel(
    const float* __restrict__ per_tok, const int* __restrict__ tgt,
    float* __restrict__ out, int N) {
  __shared__ float redf[4];
  __shared__ int redi[4];
  float s = 0.f;
  int c = 0;
  for (int i = threadIdx.x; i < N; i += 256) {
    if (tgt[i] != IGNORE_INDEX) { s += per_tok[i]; c += 1; }
  }
#pragma unroll
  for (int o = 32; o >= 1; o >>= 1) {
    s += __shfl_xor(s, o, 64);
    c += __shfl_xor(c, o, 64);
  }
  const int w = threadIdx.x >> 6;
  if ((threadIdx.x & 63) == 0) { redf[w] = s; redi[w] = c; }
  __syncthreads();
  if (threadIdx.x == 0) {
    float st = 0.f;
    int ct = 0;
#pragma unroll
    for (int i = 0; i < 4; ++i) { st += redf[i]; ct += redi[i]; }
    out[0] = st / (float)(ct > 0 ? ct : 1);
  }
}

// ---------------------------------------------------------------- launch
extern "C" void kernel_launch(void* const* d_in, const int* in_sizes, int n_in,
                              void* d_out, int out_size, void* d_ws, size_t ws_size,
                              hipStream_t stream) {
  const float* student = (const float*)d_in[0];
  const float* W_s     = (const float*)d_in[1];
  const float* teacher = (const float*)d_in[2];
  const float* W_t     = (const float*)d_in[3];
  const int*   target  = (const int*)d_in[4];

  const int N  = in_sizes[4];            // 2048
  const int Hs = in_sizes[0] / N;        // 2048
  const int Ht = in_sizes[2] / N;        // 4096
  const int V  = in_sizes[1] / Hs;       // 32000

  char* ws = (char*)d_ws;
  size_t off = 0;
  auto alloc = [&](size_t bytes) -> void* {
    void* p = ws + off;
    off += (bytes + 255) & ~(size_t)255;
    return p;
  };
  uint8_t* Sf8  = (uint8_t*)alloc((size_t)N * Hs);
  uint8_t* Wsf8 = (uint8_t*)alloc((size_t)V * Hs);
  uint8_t* Tf8  = (uint8_t*)alloc((size_t)N * Ht);
  uint8_t* Wtf8 = (uint8_t*)alloc((size_t)V * Ht);
  uint16_t* slog = (uint16_t*)alloc((size_t)N * V * 2);
  uint16_t* tlog = (uint16_t*)alloc((size_t)N * V * 2);
  float* per_tok = (float*)alloc((size_t)N * sizeof(float));
  (void)ws_size;  // total ~465 MB

  // fused convert: grid-stride, 8192-float chunks (boundaries all even
  // multiples of 4096 floats -> no chunk straddles an array)
  const int c0 = (N * Hs) / 8192;               // 512
  const int c1 = c0 + (V * Hs) / 8192;          // +8000
  const int c2 = c1 + (N * Ht) / 8192;          // +1024
  const int cT = c2 + (V * Ht) / 8192;          // +16000 = 25536
  fused_cvt_kernel<<<4096, 256, 0, stream>>>(
      student, Sf8, c0, W_s, Wsf8, c1, teacher, Tf8, c2, W_t, Wtf8, cT);

  const int RT = N / 256;   // 8
  const int CT = V / 256;   // 125
  // merged launch: teacher blocks first, student backfills the tail
  gemm_mx4_kernel<<<2 * RT * CT, 512, 0, stream>>>(
      Tf8, Wtf8, tlog, Ht, Sf8, Wsf8, slog, Hs, V, RT, CT);

  jsd_rows_kernel<<<N, 256, 0, stream>>>(slog, tlog, per_tok, V);
  finalize_kernel<<<1, 256, 0, stream>>>(per_tok, target, (float*)d_out, N);
}